// Round 1
// baseline (1351.647 us; speedup 1.0000x reference)
//
#include <hip/hip_runtime.h>
#include <math.h>

#define DIM 1024
#define T_SEQ 2048
#define NBATCH 2
#define HEADS 16
#define HD 64
#define NTOK 4096  // NBATCH * T_SEQ
#define THRESH 0.29514f
#define SHARP 15.0f

// ---------------------------------------------------------------------------
// Kernel 1: LayerNorm row statistics (mean, rstd) per token row of x.
// One wave per row, 4 rows per 256-thread block.
// ---------------------------------------------------------------------------
__global__ __launch_bounds__(256) void ln_stats_kernel(const float* __restrict__ x,
                                                       float* __restrict__ mu,
                                                       float* __restrict__ rs) {
    int row = blockIdx.x * 4 + (threadIdx.x >> 6);
    int lane = threadIdx.x & 63;
    const float4* xr = (const float4*)(x + (size_t)row * DIM);
    float s = 0.f, ss = 0.f;
#pragma unroll
    for (int i = 0; i < 4; i++) {
        float4 v = xr[lane + i * 64];
        s += v.x + v.y + v.z + v.w;
        ss += v.x * v.x + v.y * v.y + v.z * v.z + v.w * v.w;
    }
#pragma unroll
    for (int off = 32; off; off >>= 1) {
        s += __shfl_down(s, off);
        ss += __shfl_down(ss, off);
    }
    if (lane == 0) {
        float m = s * (1.f / DIM);
        float var = ss * (1.f / DIM) - m * m;
        mu[row] = m;
        rs[row] = rsqrtf(var + 1e-5f);
    }
}

// ---------------------------------------------------------------------------
// Kernel 2: fp32 tiled GEMM, 64x64 tile, 4x4 register blocking, K-step 16.
// MODE 0: A = x with optional fused LayerNorm (z=0,1 -> x_norm; z=2 -> raw x),
//         W selected by blockIdx.z, output written in [B,H,T,hd] layout.
// MODE 1: A = collapse (plain), W = Wo, + bias, output row-major [B,T,D].
// ---------------------------------------------------------------------------
template <int MODE>
__global__ __launch_bounds__(256) void gemm64_kernel(
    const float* __restrict__ A, const float* __restrict__ mu, const float* __restrict__ rs,
    const float* __restrict__ lnw, const float* __restrict__ lnb,
    const float* __restrict__ W0, const float* __restrict__ W1, const float* __restrict__ W2,
    const float* __restrict__ bias,
    float* __restrict__ O0, float* __restrict__ O1, float* __restrict__ O2) {
    __shared__ float As[16][68];  // [k][m], +4 pad: 2-way (free) write pattern
    __shared__ float Bs[16][64];  // [k][n]
    const int m0 = blockIdx.x * 64;
    const int n0 = blockIdx.y * 64;
    const float* W;
    float* O;
    bool ln = false;
    if constexpr (MODE == 0) {
        int z = blockIdx.z;
        W = (z == 0) ? W0 : (z == 1) ? W1 : W2;
        O = (z == 0) ? O0 : (z == 1) ? O1 : O2;
        ln = (z != 2);
    } else {
        W = W0;
        O = O0;
    }
    const int tid = threadIdx.x;
    const int tx = tid & 15, ty = tid >> 4;
    const int kA = tid & 15, mA = tid >> 4;   // A loader: k = kA, m = mA + {0,16,32,48}
    const int nB = tid & 63, kB = tid >> 6;   // B loader: n = nB, k = kB + {0,4,8,12}
    float acc[4][4] = {};
    float mu_r[4], rs_r[4];
    if constexpr (MODE == 0) {
        if (ln) {
#pragma unroll
            for (int i = 0; i < 4; i++) {
                mu_r[i] = mu[m0 + mA + i * 16];
                rs_r[i] = rs[m0 + mA + i * 16];
            }
        }
    }
    for (int kk = 0; kk < DIM; kk += 16) {
        __syncthreads();
        float lw = 1.f, lb = 0.f;
        if constexpr (MODE == 0) {
            if (ln) { lw = lnw[kk + kA]; lb = lnb[kk + kA]; }
        }
#pragma unroll
        for (int i = 0; i < 4; i++) {
            int m = mA + i * 16;
            float a = A[(size_t)(m0 + m) * DIM + kk + kA];
            if constexpr (MODE == 0) {
                if (ln) a = (a - mu_r[i]) * rs_r[i] * lw + lb;
            }
            As[kA][m] = a;
        }
#pragma unroll
        for (int i = 0; i < 4; i++) {
            int k = kB + i * 4;
            Bs[k][nB] = W[(size_t)(kk + k) * DIM + n0 + nB];
        }
        __syncthreads();
#pragma unroll
        for (int k = 0; k < 16; k++) {
            float4 av = *(const float4*)&As[k][ty << 2];
            float4 bv = *(const float4*)&Bs[k][tx << 2];
            float a_[4] = {av.x, av.y, av.z, av.w};
            float b_[4] = {bv.x, bv.y, bv.z, bv.w};
#pragma unroll
            for (int i = 0; i < 4; i++)
#pragma unroll
                for (int j = 0; j < 4; j++) acc[i][j] = fmaf(a_[i], b_[j], acc[i][j]);
        }
    }
    if constexpr (MODE == 0) {
        const int h = n0 >> 6;  // tile N=64 is head-aligned
#pragma unroll
        for (int i = 0; i < 4; i++) {
            int tok = m0 + (ty << 2) + i;
            int b = tok >> 11, t = tok & 2047;
            float* dst = O + ((size_t)(b * HEADS + h) * T_SEQ + t) * HD + (tx << 2);
            *(float4*)dst = make_float4(acc[i][0], acc[i][1], acc[i][2], acc[i][3]);
        }
    } else {
        int n = n0 + (tx << 2);
        float4 bv = *(const float4*)&bias[n];
#pragma unroll
        for (int i = 0; i < 4; i++) {
            int tok = m0 + (ty << 2) + i;
            *(float4*)(O + (size_t)tok * DIM + n) = make_float4(
                acc[i][0] + bv.x, acc[i][1] + bv.y, acc[i][2] + bv.z, acc[i][3] + bv.w);
        }
    }
}

// ---------------------------------------------------------------------------
// Kernel 3: per-(b,h,t) l2-normalize 64-elem row in-place + gate dot product.
// One wave per row, 4 rows per block.
// ---------------------------------------------------------------------------
__global__ __launch_bounds__(256) void l2norm_gate_kernel(float* __restrict__ Q,
                                                          const float* __restrict__ g,
                                                          float* __restrict__ gate) {
    int row = blockIdx.x * 4 + (threadIdx.x >> 6);
    int lane = threadIdx.x & 63;
    float v = Q[(size_t)row * HD + lane];
    float s = v * v;
#pragma unroll
    for (int off = 32; off; off >>= 1) s += __shfl_down(s, off);
    s = __shfl(s, 0);
    float rn = 1.f / fmaxf(sqrtf(s), 1e-12f);
    v *= rn;
    Q[(size_t)row * HD + lane] = v;
    float gg = v * g[lane];
#pragma unroll
    for (int off = 32; off; off >>= 1) gg += __shfl_down(gg, off);
    if (lane == 0) gate[row] = gg;
}

// ---------------------------------------------------------------------------
// Kernel 4: fused gated attention. Block = 32 q-rows of one (b,h).
// Chunks of 64 s-tokens: S = Q·K^T -> sigmoid gate -> C += S'·V.
// No softmax normalization in this model, so chunking is exact.
// LDS ~53.6 KB. Thread blocking: 2 (rows) x 4 (cols).
// ---------------------------------------------------------------------------
__global__ __launch_bounds__(256) void attn_kernel(
    const float* __restrict__ Q, const float* __restrict__ K, const float* __restrict__ V,
    const float* __restrict__ gateq, const float* __restrict__ gatek,
    float* __restrict__ coll) {
    __shared__ float Qs[64][36];  // [d][r], r in 0..31, pad to 36
    __shared__ float Ks[64][68];  // [d][c], c in 0..63, pad to 68
    __shared__ float Vs[64][68];  // [s][dv]
    __shared__ float Ss[64][36];  // [s][r] (gated scores)
    __shared__ float gq_s[32];
    __shared__ float gk_s[64];
    const int t0 = blockIdx.x * 32;
    const int h = blockIdx.y, b = blockIdx.z;
    const int bh = b * HEADS + h;
    const size_t base = (size_t)bh * T_SEQ * HD;
    const int tid = threadIdx.x;
    const int tx = tid & 15, ty = tid >> 4;

    // load Q tile transposed: Qs[d][r]
    for (int i = tid; i < 512; i += 256) {
        int r = i >> 4, d4 = (i & 15) << 2;
        float4 qv = *(const float4*)&Q[base + (size_t)(t0 + r) * HD + d4];
        Qs[d4 + 0][r] = qv.x;
        Qs[d4 + 1][r] = qv.y;
        Qs[d4 + 2][r] = qv.z;
        Qs[d4 + 3][r] = qv.w;
    }
    if (tid < 32) gq_s[tid] = gateq[bh * T_SEQ + t0 + tid];

    float acc0[4] = {}, acc1[4] = {};
    for (int s0 = 0; s0 < T_SEQ; s0 += 64) {
        __syncthreads();  // protect Ks/Vs/Ss from previous iteration readers
        for (int i = tid; i < 1024; i += 256) {
            int c = i >> 4, d4 = (i & 15) << 2;
            float4 kv = *(const float4*)&K[base + (size_t)(s0 + c) * HD + d4];
            Ks[d4 + 0][c] = kv.x;
            Ks[d4 + 1][c] = kv.y;
            Ks[d4 + 2][c] = kv.z;
            Ks[d4 + 3][c] = kv.w;
            float4 vv = *(const float4*)&V[base + (size_t)(s0 + c) * HD + d4];
            *(float4*)&Vs[c][d4] = vv;
        }
        if (tid < 64) gk_s[tid] = gatek[bh * T_SEQ + s0 + tid];
        __syncthreads();
        // S-phase: rows r = 2*ty + {0,1}, cols c = 4*tx + {0..3}
        float sc0[4] = {}, sc1[4] = {};
#pragma unroll
        for (int d = 0; d < 64; d++) {
            float2 qv = *(const float2*)&Qs[d][ty << 1];
            float4 kv = *(const float4*)&Ks[d][tx << 2];
            float b_[4] = {kv.x, kv.y, kv.z, kv.w};
#pragma unroll
            for (int j = 0; j < 4; j++) {
                sc0[j] = fmaf(qv.x, b_[j], sc0[j]);
                sc1[j] = fmaf(qv.y, b_[j], sc1[j]);
            }
        }
#pragma unroll
        for (int j = 0; j < 4; j++) {
            float gkc = gk_s[(tx << 2) + j];
            float2 w;
            w.x = gkc / (1.f + __expf(-(sc0[j] - THRESH) * SHARP));
            w.y = gkc / (1.f + __expf(-(sc1[j] - THRESH) * SHARP));
            *(float2*)&Ss[(tx << 2) + j][ty << 1] = w;
        }
        __syncthreads();
        // SV-phase: C[r][dv] += S'[r][s] * V[s][dv], dv = 4*tx + {0..3}
#pragma unroll
        for (int s = 0; s < 64; s++) {
            float2 sv = *(const float2*)&Ss[s][ty << 1];
            float4 vv = *(const float4*)&Vs[s][tx << 2];
            float b_[4] = {vv.x, vv.y, vv.z, vv.w};
#pragma unroll
            for (int j = 0; j < 4; j++) {
                acc0[j] = fmaf(sv.x, b_[j], acc0[j]);
                acc1[j] = fmaf(sv.y, b_[j], acc1[j]);
            }
        }
    }
    // epilogue: multiply by gate_q, write collapse in [B,T,D] layout
    {
        float g0 = gq_s[(ty << 1) + 0];
        float g1 = gq_s[(ty << 1) + 1];
        int t = t0 + (ty << 1);
        float* dst0 = coll + ((size_t)b * T_SEQ + t + 0) * DIM + h * HD + (tx << 2);
        float* dst1 = coll + ((size_t)b * T_SEQ + t + 1) * DIM + h * HD + (tx << 2);
        *(float4*)dst0 = make_float4(acc0[0] * g0, acc0[1] * g0, acc0[2] * g0, acc0[3] * g0);
        *(float4*)dst1 = make_float4(acc1[0] * g1, acc1[1] * g1, acc1[2] * g1, acc1[3] * g1);
    }
}

// ---------------------------------------------------------------------------
extern "C" void kernel_launch(void* const* d_in, const int* in_sizes, int n_in,
                              void* d_out, int out_size, void* d_ws, size_t ws_size,
                              hipStream_t stream) {
    const float* x = (const float*)d_in[0];
    const float* Wq = (const float*)d_in[1];
    const float* Wk = (const float*)d_in[2];
    const float* Wv = (const float*)d_in[3];
    const float* gq = (const float*)d_in[4];
    const float* gk = (const float*)d_in[5];
    const float* Wo = (const float*)d_in[6];
    const float* bo = (const float*)d_in[7];
    const float* lnw = (const float*)d_in[8];
    const float* lnb = (const float*)d_in[9];
    float* out = (float*)d_out;

    float* ws = (float*)d_ws;
    float* mu = ws;                       // 4096
    float* rs = mu + NTOK;                // 4096
    float* Qb = rs + NTOK;                // 4,194,304  [B,H,T,hd]
    float* Kb = Qb + (size_t)NTOK * DIM;  // 4,194,304
    float* Vb = Kb + (size_t)NTOK * DIM;  // 4,194,304
    float* gq_t = Vb + (size_t)NTOK * DIM;            // 65,536 [B,H,T]
    float* gk_t = gq_t + NBATCH * HEADS * T_SEQ;      // 65,536
    float* coll = gk_t + NBATCH * HEADS * T_SEQ;      // 4,194,304 [B,T,D]

    ln_stats_kernel<<<NTOK / 4, 256, 0, stream>>>(x, mu, rs);
    gemm64_kernel<0><<<dim3(NTOK / 64, DIM / 64, 3), 256, 0, stream>>>(
        x, mu, rs, lnw, lnb, Wq, Wk, Wv, nullptr, Qb, Kb, Vb);
    l2norm_gate_kernel<<<(NBATCH * HEADS * T_SEQ) / 4, 256, 0, stream>>>(Qb, gq, gq_t);
    l2norm_gate_kernel<<<(NBATCH * HEADS * T_SEQ) / 4, 256, 0, stream>>>(Kb, gk, gk_t);
    attn_kernel<<<dim3(T_SEQ / 32, HEADS, NBATCH), 256, 0, stream>>>(
        Qb, Kb, Vb, gq_t, gk_t, coll);
    gemm64_kernel<1><<<dim3(NTOK / 64, DIM / 64, 1), 256, 0, stream>>>(
        coll, nullptr, nullptr, nullptr, nullptr, Wo, nullptr, nullptr, bo, out, nullptr, nullptr);
}

// Round 2
// 719.757 us; speedup vs baseline: 1.8779x; 1.8779x over previous
//
#include <hip/hip_runtime.h>
#include <math.h>

#define DIM 1024
#define T_SEQ 2048
#define NBATCH 2
#define HEADS 16
#define HD 64
#define NTOK 4096  // NBATCH * T_SEQ
#define THRESH 0.29514f
#define SHARP 15.0f

typedef __attribute__((ext_vector_type(8))) short bf16x8;
typedef __attribute__((ext_vector_type(4))) float f32x4;

__device__ __forceinline__ unsigned short f2b(float f) {
    unsigned int u = __float_as_uint(f);
    unsigned int r = (u + 0x7FFFu + ((u >> 16) & 1u)) >> 16;
    return (unsigned short)r;
}
__device__ __forceinline__ float b2f(unsigned short u) {
    return __uint_as_float(((unsigned int)u) << 16);
}

// ---------------------------------------------------------------------------
// Kernel 1: LayerNorm row statistics (mean, rstd) per token row of x.
// ---------------------------------------------------------------------------
__global__ __launch_bounds__(256) void ln_stats_kernel(const float* __restrict__ x,
                                                       float* __restrict__ mu,
                                                       float* __restrict__ rs) {
    int row = blockIdx.x * 4 + (threadIdx.x >> 6);
    int lane = threadIdx.x & 63;
    const float4* xr = (const float4*)(x + (size_t)row * DIM);
    float s = 0.f, ss = 0.f;
#pragma unroll
    for (int i = 0; i < 4; i++) {
        float4 v = xr[lane + i * 64];
        s += v.x + v.y + v.z + v.w;
        ss += v.x * v.x + v.y * v.y + v.z * v.z + v.w * v.w;
    }
#pragma unroll
    for (int off = 32; off; off >>= 1) {
        s += __shfl_down(s, off);
        ss += __shfl_down(ss, off);
    }
    if (lane == 0) {
        float m = s * (1.f / DIM);
        float var = ss * (1.f / DIM) - m * m;
        mu[row] = m;
        rs[row] = rsqrtf(var + 1e-5f);
    }
}

// ---------------------------------------------------------------------------
// Kernel 2: fp32 tiled GEMM, 64x64 tile, 4x4 register blocking, K-step 16.
// MODE 0: A = x with optional fused LayerNorm (z=0,1 -> x_norm; z=2 -> raw x),
//         z=0/1 write fp32 [B,H,T,hd]; z=2 writes bf16 [B,H,T,hd] (V).
// MODE 1: A = collapse, W = Wo, + bias, fp32 out [B,T,D].
// ---------------------------------------------------------------------------
template <int MODE>
__global__ __launch_bounds__(256) void gemm64_kernel(
    const float* __restrict__ A, const float* __restrict__ mu, const float* __restrict__ rs,
    const float* __restrict__ lnw, const float* __restrict__ lnb,
    const float* __restrict__ W0, const float* __restrict__ W1, const float* __restrict__ W2,
    const float* __restrict__ bias,
    float* __restrict__ O0, float* __restrict__ O1, unsigned short* __restrict__ O2b) {
    __shared__ float As[16][68];
    __shared__ float Bs[16][64];
    const int m0 = blockIdx.x * 64;
    const int n0 = blockIdx.y * 64;
    int z = 0;
    const float* W;
    bool ln = false;
    if constexpr (MODE == 0) {
        z = blockIdx.z;
        W = (z == 0) ? W0 : (z == 1) ? W1 : W2;
        ln = (z != 2);
    } else {
        W = W0;
    }
    const int tid = threadIdx.x;
    const int tx = tid & 15, ty = tid >> 4;
    const int kA = tid & 15, mA = tid >> 4;
    const int nB = tid & 63, kB = tid >> 6;
    float acc[4][4] = {};
    float mu_r[4], rs_r[4];
    if constexpr (MODE == 0) {
        if (ln) {
#pragma unroll
            for (int i = 0; i < 4; i++) {
                mu_r[i] = mu[m0 + mA + i * 16];
                rs_r[i] = rs[m0 + mA + i * 16];
            }
        }
    }
    for (int kk = 0; kk < DIM; kk += 16) {
        __syncthreads();
        float lw = 1.f, lb = 0.f;
        if constexpr (MODE == 0) {
            if (ln) { lw = lnw[kk + kA]; lb = lnb[kk + kA]; }
        }
#pragma unroll
        for (int i = 0; i < 4; i++) {
            int m = mA + i * 16;
            float a = A[(size_t)(m0 + m) * DIM + kk + kA];
            if constexpr (MODE == 0) {
                if (ln) a = (a - mu_r[i]) * rs_r[i] * lw + lb;
            }
            As[kA][m] = a;
        }
#pragma unroll
        for (int i = 0; i < 4; i++) {
            int k = kB + i * 4;
            Bs[k][nB] = W[(size_t)(kk + k) * DIM + n0 + nB];
        }
        __syncthreads();
#pragma unroll
        for (int k = 0; k < 16; k++) {
            float4 av = *(const float4*)&As[k][ty << 2];
            float4 bv = *(const float4*)&Bs[k][tx << 2];
            float a_[4] = {av.x, av.y, av.z, av.w};
            float b_[4] = {bv.x, bv.y, bv.z, bv.w};
#pragma unroll
            for (int i = 0; i < 4; i++)
#pragma unroll
                for (int j = 0; j < 4; j++) acc[i][j] = fmaf(a_[i], b_[j], acc[i][j]);
        }
    }
    if constexpr (MODE == 0) {
        const int h = n0 >> 6;
#pragma unroll
        for (int i = 0; i < 4; i++) {
            int tok = m0 + (ty << 2) + i;
            int b = tok >> 11, t = tok & 2047;
            size_t off = ((size_t)(b * HEADS + h) * T_SEQ + t) * HD + (tx << 2);
            if (z == 2) {
                ushort4 u;
                u.x = f2b(acc[i][0]); u.y = f2b(acc[i][1]);
                u.z = f2b(acc[i][2]); u.w = f2b(acc[i][3]);
                *(ushort4*)(O2b + off) = u;
            } else {
                float* dst = ((z == 0) ? O0 : O1) + off;
                *(float4*)dst = make_float4(acc[i][0], acc[i][1], acc[i][2], acc[i][3]);
            }
        }
    } else {
        int n = n0 + (tx << 2);
        float4 bv = *(const float4*)&bias[n];
#pragma unroll
        for (int i = 0; i < 4; i++) {
            int tok = m0 + (ty << 2) + i;
            *(float4*)(O0 + (size_t)tok * DIM + n) = make_float4(
                acc[i][0] + bv.x, acc[i][1] + bv.y, acc[i][2] + bv.z, acc[i][3] + bv.w);
        }
    }
}

// ---------------------------------------------------------------------------
// Kernel 3: per-(b,h,t) l2-normalize 64-elem row -> bf16 out + gate dot.
// ---------------------------------------------------------------------------
__global__ __launch_bounds__(256) void l2norm_gate_bf16_kernel(
    const float* __restrict__ Q, const float* __restrict__ g,
    unsigned short* __restrict__ Qn, float* __restrict__ gate) {
    int row = blockIdx.x * 4 + (threadIdx.x >> 6);
    int lane = threadIdx.x & 63;
    float v = Q[(size_t)row * HD + lane];
    float s = v * v;
#pragma unroll
    for (int off = 32; off; off >>= 1) s += __shfl_down(s, off);
    s = __shfl(s, 0);
    float rn = 1.f / fmaxf(sqrtf(s), 1e-12f);
    float vn = v * rn;
    Qn[(size_t)row * HD + lane] = f2b(vn);
    float gg = vn * g[lane];
#pragma unroll
    for (int off = 32; off; off >>= 1) gg += __shfl_down(gg, off);
    if (lane == 0) gate[row] = gg;
}

// ---------------------------------------------------------------------------
// Kernel 4: bf16 transpose V[bh][t][d] -> Vt[bh][d][t] via fp32 LDS tile
// (4-byte elements + stride 65 => conflict-free both directions).
// ---------------------------------------------------------------------------
__global__ __launch_bounds__(256) void vtrans_kernel(const unsigned short* __restrict__ Vn,
                                                     unsigned short* __restrict__ Vt) {
    __shared__ float tile[64][65];
    const int bh = blockIdx.y;
    const int t0 = blockIdx.x * 64;
    const int r = threadIdx.x >> 3;
    const int c = (threadIdx.x & 7) * 8;
    const unsigned short* src = Vn + (size_t)bh * T_SEQ * HD;
#pragma unroll
    for (int half = 0; half < 2; half++) {
        int rr = r + half * 32;
        bf16x8 v = *(const bf16x8*)(src + (size_t)(t0 + rr) * HD + c);
#pragma unroll
        for (int j = 0; j < 8; j++) tile[rr][c + j] = b2f((unsigned short)v[j]);
    }
    __syncthreads();
    unsigned short* dst = Vt + (size_t)bh * HD * T_SEQ;
#pragma unroll
    for (int half = 0; half < 2; half++) {
        int dd = r + half * 32;
        bf16x8 o;
#pragma unroll
        for (int j = 0; j < 8; j++) o[j] = (short)f2b(tile[c + j][dd]);
        *(bf16x8*)(dst + (size_t)dd * T_SEQ + t0 + c) = o;
    }
}

// ---------------------------------------------------------------------------
// Kernel 5: MFMA gated attention.
// Block = 256 thr = 4 waves, 64 q-rows of one (b,h); wave w owns rows w*16..+15.
// s-chunks of 64: stage K rows + Vt rows in LDS (stride 72 bf16), QK^T via
// 2x mfma_16x16x32_bf16 per 16-col tile, sigmoid*gate_k in registers,
// bf16 S through per-wave LDS (C-layout -> A-layout), then S·V MFMA.
// gate_q applied at epilogue. No softmax normalization => chunking exact.
// ---------------------------------------------------------------------------
__global__ __launch_bounds__(256) void attn_mfma_kernel(
    const unsigned short* __restrict__ Qn, const unsigned short* __restrict__ Kn,
    const unsigned short* __restrict__ Vt, const float* __restrict__ gateq,
    const float* __restrict__ gatek, float* __restrict__ coll) {
    __shared__ __align__(16) unsigned short Ks[64 * 72];   // [s][d] stride 72
    __shared__ __align__(16) unsigned short VtL[64 * 72];  // [d][s] stride 72
    __shared__ __align__(16) unsigned short Sw[4 * 16 * 72];  // per-wave [m][s]
    __shared__ float gk_s[64];
    const int tid = threadIdx.x;
    const int lane = tid & 63, w = tid >> 6;
    const int quad = lane >> 4, l16 = lane & 15;
    const int t0 = blockIdx.x * 64;
    const int h = blockIdx.y, b = blockIdx.z;
    const int bh = b * HEADS + h;
    const size_t base = (size_t)bh * T_SEQ * HD;  // also == bh*HD*T_SEQ for Vt

    // Q A-fragments (held in registers for whole kernel)
    const unsigned short* qrow = Qn + base + (size_t)(t0 + w * 16 + l16) * HD;
    bf16x8 fq0 = *(const bf16x8*)(qrow + quad * 8);
    bf16x8 fq1 = *(const bf16x8*)(qrow + 32 + quad * 8);

    f32x4 oacc[4] = {};
    unsigned short* myS = &Sw[w * 16 * 72];

    const int sr = tid >> 3;            // staging row 0..31
    const int sc = (tid & 7) * 8;       // staging col

    for (int s0 = 0; s0 < T_SEQ; s0 += 64) {
        __syncthreads();  // previous-iter readers done before overwrite
#pragma unroll
        for (int half = 0; half < 2; half++) {
            int rr = sr + half * 32;
            bf16x8 kv = *(const bf16x8*)(Kn + base + (size_t)(s0 + rr) * HD + sc);
            *(bf16x8*)(Ks + rr * 72 + sc) = kv;
            bf16x8 vv = *(const bf16x8*)(Vt + base + (size_t)rr * T_SEQ + s0 + sc);
            *(bf16x8*)(VtL + rr * 72 + sc) = vv;
        }
        if (tid < 64) gk_s[tid] = gatek[bh * T_SEQ + s0 + tid];
        __syncthreads();

        // ---- S-phase: align = Q K^T, gate, write bf16 S to per-wave LDS ----
#pragma unroll
        for (int ct = 0; ct < 4; ct++) {
            f32x4 sacc = {0.f, 0.f, 0.f, 0.f};
            bf16x8 fk0 = *(const bf16x8*)(Ks + (ct * 16 + l16) * 72 + quad * 8);
            bf16x8 fk1 = *(const bf16x8*)(Ks + (ct * 16 + l16) * 72 + 32 + quad * 8);
            sacc = __builtin_amdgcn_mfma_f32_16x16x32_bf16(fq0, fk0, sacc, 0, 0, 0);
            sacc = __builtin_amdgcn_mfma_f32_16x16x32_bf16(fq1, fk1, sacc, 0, 0, 0);
            float gkc = gk_s[ct * 16 + l16];
#pragma unroll
            for (int r = 0; r < 4; r++) {
                float wv = gkc / (1.f + __expf((THRESH - sacc[r]) * SHARP));
                myS[(quad * 4 + r) * 72 + ct * 16 + l16] = f2b(wv);
            }
        }
        __syncthreads();  // S visible (also keeps staging uniform)

        // ---- SV-phase: O += S V ----
        bf16x8 fs0 = *(const bf16x8*)(myS + l16 * 72 + quad * 8);
        bf16x8 fs1 = *(const bf16x8*)(myS + l16 * 72 + 32 + quad * 8);
#pragma unroll
        for (int dt = 0; dt < 4; dt++) {
            bf16x8 fv0 = *(const bf16x8*)(VtL + (dt * 16 + l16) * 72 + quad * 8);
            bf16x8 fv1 = *(const bf16x8*)(VtL + (dt * 16 + l16) * 72 + 32 + quad * 8);
            oacc[dt] = __builtin_amdgcn_mfma_f32_16x16x32_bf16(fs0, fv0, oacc[dt], 0, 0, 0);
            oacc[dt] = __builtin_amdgcn_mfma_f32_16x16x32_bf16(fs1, fv1, oacc[dt], 0, 0, 0);
        }
    }

    // ---- epilogue: * gate_q, write collapse [B,T,D] fp32 ----
#pragma unroll
    for (int r = 0; r < 4; r++) {
        int t = t0 + w * 16 + quad * 4 + r;
        float gq_v = gateq[bh * T_SEQ + t];
        float* dst = coll + ((size_t)b * T_SEQ + t) * DIM + h * HD;
#pragma unroll
        for (int dt = 0; dt < 4; dt++) dst[dt * 16 + l16] = oacc[dt][r] * gq_v;
    }
}

// ---------------------------------------------------------------------------
extern "C" void kernel_launch(void* const* d_in, const int* in_sizes, int n_in,
                              void* d_out, int out_size, void* d_ws, size_t ws_size,
                              hipStream_t stream) {
    const float* x = (const float*)d_in[0];
    const float* Wq = (const float*)d_in[1];
    const float* Wk = (const float*)d_in[2];
    const float* Wv = (const float*)d_in[3];
    const float* gq = (const float*)d_in[4];
    const float* gk = (const float*)d_in[5];
    const float* Wo = (const float*)d_in[6];
    const float* bo = (const float*)d_in[7];
    const float* lnw = (const float*)d_in[8];
    const float* lnb = (const float*)d_in[9];
    float* out = (float*)d_out;

    // Workspace layout (alias-packed, ~56.5 MB; sequential stream ordering
    // makes the aliases safe: coll overwrites Qb only after l2norm(Q) read it;
    // Vt overwrites Kb only after l2norm(K) read it).
    float* ws = (float*)d_ws;
    float* mu = ws;                                   // 4096
    float* rs = mu + NTOK;                            // 4096
    float* Qb = rs + NTOK;                            // 4.19M fp32 [B,H,T,hd]
    float* Kb = Qb + (size_t)NTOK * DIM;              // 4.19M fp32
    float* gq_t = Kb + (size_t)NTOK * DIM;            // 65536 [B,H,T]
    float* gk_t = gq_t + NBATCH * HEADS * T_SEQ;      // 65536
    unsigned short* Qn = (unsigned short*)(gk_t + NBATCH * HEADS * T_SEQ);
    unsigned short* Kn = Qn + (size_t)NTOK * DIM;     // bf16 [B,H,T,hd]
    unsigned short* Vn = Kn + (size_t)NTOK * DIM;     // bf16 [B,H,T,hd]
    unsigned short* Vt = (unsigned short*)Kb;         // alias: bf16 [B,H,hd,T]
    float* coll = Qb;                                 // alias: fp32 [B,T,D]

    ln_stats_kernel<<<NTOK / 4, 256, 0, stream>>>(x, mu, rs);
    gemm64_kernel<0><<<dim3(NTOK / 64, DIM / 64, 3), 256, 0, stream>>>(
        x, mu, rs, lnw, lnb, Wq, Wk, Wv, nullptr, Qb, Kb, Vn);
    l2norm_gate_bf16_kernel<<<(NBATCH * HEADS * T_SEQ) / 4, 256, 0, stream>>>(Qb, gq, Qn, gq_t);
    l2norm_gate_bf16_kernel<<<(NBATCH * HEADS * T_SEQ) / 4, 256, 0, stream>>>(Kb, gk, Kn, gk_t);
    vtrans_kernel<<<dim3(T_SEQ / 64, NBATCH * HEADS), 256, 0, stream>>>(Vn, Vt);
    attn_mfma_kernel<<<dim3(T_SEQ / 64, HEADS, NBATCH), 256, 0, stream>>>(
        Qn, Kn, Vt, gq_t, gk_t, coll);
    gemm64_kernel<1><<<dim3(NTOK / 64, DIM / 64, 1), 256, 0, stream>>>(
        coll, nullptr, nullptr, nullptr, nullptr, Wo, nullptr, nullptr, bo, out, nullptr, nullptr);
}

// Round 3
// 277.860 us; speedup vs baseline: 4.8645x; 2.5904x over previous
//
#include <hip/hip_runtime.h>
#include <math.h>

#define DIM 1024
#define T_SEQ 2048
#define NBATCH 2
#define HEADS 16
#define HD 64
#define NTOK 4096  // NBATCH * T_SEQ
#define THRESH 0.29514f
#define SHARP 15.0f

typedef __attribute__((ext_vector_type(8))) short bf16x8;
typedef __attribute__((ext_vector_type(4))) float f32x4;

__device__ __forceinline__ unsigned short f2b(float f) {
    unsigned int u = __float_as_uint(f);
    unsigned int r = (u + 0x7FFFu + ((u >> 16) & 1u)) >> 16;
    return (unsigned short)r;
}
__device__ __forceinline__ float b2f(unsigned short u) {
    return __uint_as_float(((unsigned int)u) << 16);
}

__device__ __forceinline__ void async_cp16(const unsigned short* g, unsigned short* l) {
    __builtin_amdgcn_global_load_lds(
        (const __attribute__((address_space(1))) unsigned int*)g,
        (__attribute__((address_space(3))) unsigned int*)l, 16, 0, 0);
}

// ---------------------------------------------------------------------------
// Kernel 1: fused LayerNorm -> bf16 x_norm, plus bf16 cast of raw x.
// One wave per row, 4 rows per block.
// ---------------------------------------------------------------------------
__global__ __launch_bounds__(256) void ln_xnorm_kernel(
    const float* __restrict__ x, const float* __restrict__ lnw, const float* __restrict__ lnb,
    unsigned short* __restrict__ xnb, unsigned short* __restrict__ xb) {
    int row = blockIdx.x * 4 + (threadIdx.x >> 6);
    int lane = threadIdx.x & 63;
    const float4* xr = (const float4*)(x + (size_t)row * DIM);
    float4 v[4];
    float s = 0.f, ss = 0.f;
#pragma unroll
    for (int i = 0; i < 4; i++) {
        v[i] = xr[lane + i * 64];
        s += v[i].x + v[i].y + v[i].z + v[i].w;
        ss += v[i].x * v[i].x + v[i].y * v[i].y + v[i].z * v[i].z + v[i].w * v[i].w;
    }
#pragma unroll
    for (int off = 32; off; off >>= 1) {
        s += __shfl_xor(s, off);
        ss += __shfl_xor(ss, off);
    }
    float m = s * (1.f / DIM);
    float rstd = rsqrtf(ss * (1.f / DIM) - m * m + 1e-5f);
#pragma unroll
    for (int i = 0; i < 4; i++) {
        int e = (lane + i * 64) * 4;
        float4 lw = *(const float4*)&lnw[e];
        float4 lb = *(const float4*)&lnb[e];
        ushort4 un, ur;
        un.x = f2b((v[i].x - m) * rstd * lw.x + lb.x);
        un.y = f2b((v[i].y - m) * rstd * lw.y + lb.y);
        un.z = f2b((v[i].z - m) * rstd * lw.z + lb.z);
        un.w = f2b((v[i].w - m) * rstd * lw.w + lb.w);
        ur.x = f2b(v[i].x); ur.y = f2b(v[i].y); ur.z = f2b(v[i].z); ur.w = f2b(v[i].w);
        *(ushort4*)&xnb[(size_t)row * DIM + e] = un;
        *(ushort4*)&xb[(size_t)row * DIM + e] = ur;
    }
}

// ---------------------------------------------------------------------------
// Kernel 2: fp32 [K][N] weight -> bf16 transposed [N][K], via fp32 LDS tile.
// z selects which of 4 weights. Grid (16,16,4).
// ---------------------------------------------------------------------------
__global__ __launch_bounds__(256) void wtrans_kernel(
    const float* __restrict__ W0, const float* __restrict__ W1,
    const float* __restrict__ W2, const float* __restrict__ W3,
    unsigned short* __restrict__ T0, unsigned short* __restrict__ T1,
    unsigned short* __restrict__ T2, unsigned short* __restrict__ T3) {
    __shared__ float tile[64][65];
    const int z = blockIdx.z;
    const float* W = (z == 0) ? W0 : (z == 1) ? W1 : (z == 2) ? W2 : W3;
    unsigned short* T = (z == 0) ? T0 : (z == 1) ? T1 : (z == 2) ? T2 : T3;
    const int k0 = blockIdx.x * 64, n0 = blockIdx.y * 64;
    const int r = threadIdx.x >> 3;
    const int c = (threadIdx.x & 7) * 8;
#pragma unroll
    for (int half = 0; half < 2; half++) {
        int rr = r + half * 32;
        float4 a = *(const float4*)&W[(size_t)(k0 + rr) * DIM + n0 + c];
        float4 b = *(const float4*)&W[(size_t)(k0 + rr) * DIM + n0 + c + 4];
        tile[rr][c + 0] = a.x; tile[rr][c + 1] = a.y; tile[rr][c + 2] = a.z; tile[rr][c + 3] = a.w;
        tile[rr][c + 4] = b.x; tile[rr][c + 5] = b.y; tile[rr][c + 6] = b.z; tile[rr][c + 7] = b.w;
    }
    __syncthreads();
#pragma unroll
    for (int half = 0; half < 2; half++) {
        int dd = r + half * 32;
        bf16x8 o;
#pragma unroll
        for (int j = 0; j < 8; j++) o[j] = (short)f2b(tile[c + j][dd]);
        *(bf16x8*)&T[(size_t)(n0 + dd) * DIM + k0 + c] = o;
    }
}

// ---------------------------------------------------------------------------
// Kernel 3: bf16 MFMA GEMM, 128x128 tile, BK=32, 4 waves (2x2), m97-style
// global_load_lds staging with XOR k-group swizzle (2-way/free ds_read_b128).
// MODE 0: C = A @ Bt^T for z in {0,1,2} (A = xnb for q,k; xb for v),
//         output bf16 in [B,H,T,hd] layout.
// MODE 1: C = collb @ Wot^T + bias, fp32 out [B,T,D].
// ---------------------------------------------------------------------------
template <int MODE>
__global__ __launch_bounds__(256) void gemm_mfma_kernel(
    const unsigned short* __restrict__ A0, const unsigned short* __restrict__ A2,
    const unsigned short* __restrict__ Bt0, const unsigned short* __restrict__ Bt1,
    const unsigned short* __restrict__ Bt2, const float* __restrict__ bias,
    unsigned short* __restrict__ Oq, unsigned short* __restrict__ Ok,
    unsigned short* __restrict__ Ov, float* __restrict__ Oout) {
    __shared__ __align__(16) unsigned short As[128 * 32];
    __shared__ __align__(16) unsigned short Bs[128 * 32];
    const int tid = threadIdx.x;
    const int lane = tid & 63, w = tid >> 6;
    const int l16 = lane & 15, quad = lane >> 4;
    const int wm = w >> 1, wn = w & 1;
    const int m0 = blockIdx.x * 128, n0 = blockIdx.y * 128;
    const unsigned short* A;
    const unsigned short* Bt;
    int z = 0;
    if constexpr (MODE == 0) {
        z = blockIdx.z;
        A = (z == 2) ? A2 : A0;
        Bt = (z == 0) ? Bt0 : (z == 1) ? Bt1 : Bt2;
    } else {
        A = A0;
        Bt = Bt0;
    }
    f32x4 acc[4][4] = {};
    const int kswz = (l16 >> 1) & 3;

    for (int k0 = 0; k0 < DIM; k0 += 32) {
        __syncthreads();
#pragma unroll
        for (int i = 0; i < 2; i++) {
            int linear = i * 256 + tid;
            int m = linear >> 2, kgp = linear & 3;
            int kgl = kgp ^ ((m >> 1) & 3);  // physical slot kgp holds logical kgl
            async_cp16(A + (size_t)(m0 + m) * DIM + k0 + kgl * 8, As + linear * 8);
            async_cp16(Bt + (size_t)(n0 + m) * DIM + k0 + kgl * 8, Bs + linear * 8);
        }
        __syncthreads();
        bf16x8 af[4], bfr[4];
#pragma unroll
        for (int t = 0; t < 4; t++) {
            int ma = wm * 64 + t * 16 + l16;
            af[t] = *(const bf16x8*)(As + ma * 32 + ((quad ^ kswz) * 8));
            int nb = wn * 64 + t * 16 + l16;
            bfr[t] = *(const bf16x8*)(Bs + nb * 32 + ((quad ^ kswz) * 8));
        }
#pragma unroll
        for (int mt = 0; mt < 4; mt++)
#pragma unroll
            for (int nt = 0; nt < 4; nt++)
                acc[mt][nt] =
                    __builtin_amdgcn_mfma_f32_16x16x32_bf16(af[mt], bfr[nt], acc[mt][nt], 0, 0, 0);
    }

    if constexpr (MODE == 0) {
        unsigned short* O = (z == 0) ? Oq : (z == 1) ? Ok : Ov;
#pragma unroll
        for (int mt = 0; mt < 4; mt++) {
#pragma unroll
            for (int r = 0; r < 4; r++) {
                int tok = m0 + wm * 64 + mt * 16 + quad * 4 + r;
                int b = tok >> 11, t = tok & 2047;
#pragma unroll
                for (int nt = 0; nt < 4; nt++) {
                    int n = n0 + wn * 64 + nt * 16 + l16;
                    int h = n >> 6, d = n & 63;
                    O[((size_t)(b * HEADS + h) * T_SEQ + t) * HD + d] = f2b(acc[mt][nt][r]);
                }
            }
        }
    } else {
        float bias_r[4];
#pragma unroll
        for (int nt = 0; nt < 4; nt++) bias_r[nt] = bias[n0 + wn * 64 + nt * 16 + l16];
#pragma unroll
        for (int mt = 0; mt < 4; mt++) {
#pragma unroll
            for (int r = 0; r < 4; r++) {
                int tok = m0 + wm * 64 + mt * 16 + quad * 4 + r;
#pragma unroll
                for (int nt = 0; nt < 4; nt++) {
                    int n = n0 + wn * 64 + nt * 16 + l16;
                    Oout[(size_t)tok * DIM + n] = acc[mt][nt][r] + bias_r[nt];
                }
            }
        }
    }
}

// ---------------------------------------------------------------------------
// Kernel 4: per-(b,h,t) l2-normalize 64-elem bf16 row in-place + gate dot.
// ---------------------------------------------------------------------------
__global__ __launch_bounds__(256) void l2norm_gate_kernel(
    unsigned short* __restrict__ Q, const float* __restrict__ g, float* __restrict__ gate) {
    int row = blockIdx.x * 4 + (threadIdx.x >> 6);
    int lane = threadIdx.x & 63;
    float v = b2f(Q[(size_t)row * HD + lane]);
    float s = v * v;
#pragma unroll
    for (int off = 32; off; off >>= 1) s += __shfl_xor(s, off);
    float rn = 1.f / fmaxf(sqrtf(s), 1e-12f);
    float vn = v * rn;
    Q[(size_t)row * HD + lane] = f2b(vn);
    float gg = vn * g[lane];
#pragma unroll
    for (int off = 32; off; off >>= 1) gg += __shfl_xor(gg, off);
    if (lane == 0) gate[row] = gg;
}

// ---------------------------------------------------------------------------
// Kernel 5: bf16 transpose V[bh][t][d] -> Vt[bh][d][t] via fp32 LDS tile.
// ---------------------------------------------------------------------------
__global__ __launch_bounds__(256) void vtrans_kernel(const unsigned short* __restrict__ Vn,
                                                     unsigned short* __restrict__ Vt) {
    __shared__ float tile[64][65];
    const int bh = blockIdx.y;
    const int t0 = blockIdx.x * 64;
    const int r = threadIdx.x >> 3;
    const int c = (threadIdx.x & 7) * 8;
    const unsigned short* src = Vn + (size_t)bh * T_SEQ * HD;
#pragma unroll
    for (int half = 0; half < 2; half++) {
        int rr = r + half * 32;
        bf16x8 v = *(const bf16x8*)(src + (size_t)(t0 + rr) * HD + c);
#pragma unroll
        for (int j = 0; j < 8; j++) tile[rr][c + j] = b2f((unsigned short)v[j]);
    }
    __syncthreads();
    unsigned short* dst = Vt + (size_t)bh * HD * T_SEQ;
#pragma unroll
    for (int half = 0; half < 2; half++) {
        int dd = r + half * 32;
        bf16x8 o;
#pragma unroll
        for (int j = 0; j < 8; j++) o[j] = (short)f2b(tile[c + j][dd]);
        *(bf16x8*)(dst + (size_t)dd * T_SEQ + t0 + c) = o;
    }
}

// ---------------------------------------------------------------------------
// Kernel 6: MFMA gated attention (as R2) with bf16 collapse epilogue.
// ---------------------------------------------------------------------------
__global__ __launch_bounds__(256) void attn_mfma_kernel(
    const unsigned short* __restrict__ Qn, const unsigned short* __restrict__ Kn,
    const unsigned short* __restrict__ Vt, const float* __restrict__ gateq,
    const float* __restrict__ gatek, unsigned short* __restrict__ collb) {
    __shared__ __align__(16) unsigned short Ks[64 * 72];
    __shared__ __align__(16) unsigned short VtL[64 * 72];
    __shared__ __align__(16) unsigned short Sw[4 * 16 * 72];
    __shared__ float gk_s[64];
    const int tid = threadIdx.x;
    const int lane = tid & 63, w = tid >> 6;
    const int quad = lane >> 4, l16 = lane & 15;
    const int t0 = blockIdx.x * 64;
    const int h = blockIdx.y, b = blockIdx.z;
    const int bh = b * HEADS + h;
    const size_t base = (size_t)bh * T_SEQ * HD;

    const unsigned short* qrow = Qn + base + (size_t)(t0 + w * 16 + l16) * HD;
    bf16x8 fq0 = *(const bf16x8*)(qrow + quad * 8);
    bf16x8 fq1 = *(const bf16x8*)(qrow + 32 + quad * 8);

    f32x4 oacc[4] = {};
    unsigned short* myS = &Sw[w * 16 * 72];
    const int sr = tid >> 3;
    const int sc = (tid & 7) * 8;

    for (int s0 = 0; s0 < T_SEQ; s0 += 64) {
        __syncthreads();
#pragma unroll
        for (int half = 0; half < 2; half++) {
            int rr = sr + half * 32;
            bf16x8 kv = *(const bf16x8*)(Kn + base + (size_t)(s0 + rr) * HD + sc);
            *(bf16x8*)(Ks + rr * 72 + sc) = kv;
            bf16x8 vv = *(const bf16x8*)(Vt + base + (size_t)rr * T_SEQ + s0 + sc);
            *(bf16x8*)(VtL + rr * 72 + sc) = vv;
        }
        if (tid < 64) gk_s[tid] = gatek[bh * T_SEQ + s0 + tid];
        __syncthreads();

#pragma unroll
        for (int ct = 0; ct < 4; ct++) {
            f32x4 sacc = {0.f, 0.f, 0.f, 0.f};
            bf16x8 fk0 = *(const bf16x8*)(Ks + (ct * 16 + l16) * 72 + quad * 8);
            bf16x8 fk1 = *(const bf16x8*)(Ks + (ct * 16 + l16) * 72 + 32 + quad * 8);
            sacc = __builtin_amdgcn_mfma_f32_16x16x32_bf16(fq0, fk0, sacc, 0, 0, 0);
            sacc = __builtin_amdgcn_mfma_f32_16x16x32_bf16(fq1, fk1, sacc, 0, 0, 0);
            float gkc = gk_s[ct * 16 + l16];
#pragma unroll
            for (int r = 0; r < 4; r++) {
                float wv = gkc / (1.f + __expf((THRESH - sacc[r]) * SHARP));
                myS[(quad * 4 + r) * 72 + ct * 16 + l16] = f2b(wv);
            }
        }
        __syncthreads();

        bf16x8 fs0 = *(const bf16x8*)(myS + l16 * 72 + quad * 8);
        bf16x8 fs1 = *(const bf16x8*)(myS + l16 * 72 + 32 + quad * 8);
#pragma unroll
        for (int dt = 0; dt < 4; dt++) {
            bf16x8 fv0 = *(const bf16x8*)(VtL + (dt * 16 + l16) * 72 + quad * 8);
            bf16x8 fv1 = *(const bf16x8*)(VtL + (dt * 16 + l16) * 72 + 32 + quad * 8);
            oacc[dt] = __builtin_amdgcn_mfma_f32_16x16x32_bf16(fs0, fv0, oacc[dt], 0, 0, 0);
            oacc[dt] = __builtin_amdgcn_mfma_f32_16x16x32_bf16(fs1, fv1, oacc[dt], 0, 0, 0);
        }
    }

#pragma unroll
    for (int r = 0; r < 4; r++) {
        int t = t0 + w * 16 + quad * 4 + r;
        float gq_v = gateq[bh * T_SEQ + t];
        unsigned short* dst = collb + ((size_t)b * T_SEQ + t) * DIM + h * HD;
#pragma unroll
        for (int dt = 0; dt < 4; dt++) dst[dt * 16 + l16] = f2b(oacc[dt][r] * gq_v);
    }
}

// ---------------------------------------------------------------------------
extern "C" void kernel_launch(void* const* d_in, const int* in_sizes, int n_in,
                              void* d_out, int out_size, void* d_ws, size_t ws_size,
                              hipStream_t stream) {
    const float* x = (const float*)d_in[0];
    const float* Wq = (const float*)d_in[1];
    const float* Wk = (const float*)d_in[2];
    const float* Wv = (const float*)d_in[3];
    const float* gq = (const float*)d_in[4];
    const float* gk = (const float*)d_in[5];
    const float* Wo = (const float*)d_in[6];
    const float* bo = (const float*)d_in[7];
    const float* lnw = (const float*)d_in[8];
    const float* lnb = (const float*)d_in[9];
    float* out = (float*)d_out;

    // Workspace ~51 MB (R2 used 59.4 MB successfully). Aliases safe by
    // stream ordering: Vt overwrites xnb (dead after QKV GEMM); collb
    // overwrites xb (dead after QKV GEMM).
    unsigned short* ws = (unsigned short*)d_ws;
    unsigned short* xnb = ws;                           // bf16 [4096][1024]
    unsigned short* xb = xnb + (size_t)NTOK * DIM;      // bf16 [4096][1024]
    unsigned short* Wqt = xb + (size_t)NTOK * DIM;      // bf16 [1024][1024] (W^T)
    unsigned short* Wkt = Wqt + (size_t)DIM * DIM;
    unsigned short* Wvt = Wkt + (size_t)DIM * DIM;
    unsigned short* Wot = Wvt + (size_t)DIM * DIM;
    unsigned short* Q16 = Wot + (size_t)DIM * DIM;      // bf16 [B,H,T,hd]
    unsigned short* K16 = Q16 + (size_t)NTOK * DIM;
    unsigned short* Vn = K16 + (size_t)NTOK * DIM;
    float* gq_t = (float*)(Vn + (size_t)NTOK * DIM);    // [B,H,T]
    float* gk_t = gq_t + NBATCH * HEADS * T_SEQ;
    unsigned short* Vt = xnb;    // alias
    unsigned short* collb = xb;  // alias

    ln_xnorm_kernel<<<NTOK / 4, 256, 0, stream>>>(x, lnw, lnb, xnb, xb);
    wtrans_kernel<<<dim3(16, 16, 4), 256, 0, stream>>>(Wq, Wk, Wv, Wo, Wqt, Wkt, Wvt, Wot);
    gemm_mfma_kernel<0><<<dim3(NTOK / 128, DIM / 128, 3), 256, 0, stream>>>(
        xnb, xb, Wqt, Wkt, Wvt, nullptr, Q16, K16, Vn, nullptr);
    l2norm_gate_kernel<<<(NBATCH * HEADS * T_SEQ) / 4, 256, 0, stream>>>(Q16, gq, gq_t);
    l2norm_gate_kernel<<<(NBATCH * HEADS * T_SEQ) / 4, 256, 0, stream>>>(K16, gk, gk_t);
    vtrans_kernel<<<dim3(T_SEQ / 64, NBATCH * HEADS), 256, 0, stream>>>(Vn, Vt);
    attn_mfma_kernel<<<dim3(T_SEQ / 64, HEADS, NBATCH), 256, 0, stream>>>(
        Q16, K16, Vt, gq_t, gk_t, collb);
    gemm_mfma_kernel<1><<<dim3(NTOK / 128, DIM / 128, 1), 256, 0, stream>>>(
        collb, nullptr, Wot, nullptr, nullptr, bo, nullptr, nullptr, nullptr, out);
}

// Round 5
// 250.844 us; speedup vs baseline: 5.3884x; 1.1077x over previous
//
#include <hip/hip_runtime.h>
#include <math.h>

#define DIM 1024
#define T_SEQ 2048
#define NBATCH 2
#define HEADS 16
#define HD 64
#define NTOK 4096  // NBATCH * T_SEQ
#define THRESH 0.29514f
#define SHARP 15.0f
#define LOG2E 1.4426950408889634f

typedef __attribute__((ext_vector_type(8))) short bf16x8;
typedef __attribute__((ext_vector_type(4))) float f32x4;

__device__ __forceinline__ unsigned short f2b(float f) {
    unsigned int u = __float_as_uint(f);
    unsigned int r = (u + 0x7FFFu + ((u >> 16) & 1u)) >> 16;
    return (unsigned short)r;
}
__device__ __forceinline__ float b2f(unsigned short u) {
    return __uint_as_float(((unsigned int)u) << 16);
}

__device__ __forceinline__ void async_cp16(const unsigned short* g, unsigned short* l) {
    __builtin_amdgcn_global_load_lds(
        (const __attribute__((address_space(1))) unsigned int*)g,
        (__attribute__((address_space(3))) unsigned int*)l, 16, 0, 0);
}

// ---------------------------------------------------------------------------
// Kernel 1: fused LayerNorm -> bf16 x_norm, plus bf16 cast of raw x.
// ---------------------------------------------------------------------------
__global__ __launch_bounds__(256) void ln_xnorm_kernel(
    const float* __restrict__ x, const float* __restrict__ lnw, const float* __restrict__ lnb,
    unsigned short* __restrict__ xnb, unsigned short* __restrict__ xb) {
    int row = blockIdx.x * 4 + (threadIdx.x >> 6);
    int lane = threadIdx.x & 63;
    const float4* xr = (const float4*)(x + (size_t)row * DIM);
    float4 v[4];
    float s = 0.f, ss = 0.f;
#pragma unroll
    for (int i = 0; i < 4; i++) {
        v[i] = xr[lane + i * 64];
        s += v[i].x + v[i].y + v[i].z + v[i].w;
        ss += v[i].x * v[i].x + v[i].y * v[i].y + v[i].z * v[i].z + v[i].w * v[i].w;
    }
#pragma unroll
    for (int off = 32; off; off >>= 1) {
        s += __shfl_xor(s, off);
        ss += __shfl_xor(ss, off);
    }
    float m = s * (1.f / DIM);
    float rstd = rsqrtf(ss * (1.f / DIM) - m * m + 1e-5f);
#pragma unroll
    for (int i = 0; i < 4; i++) {
        int e = (lane + i * 64) * 4;
        float4 lw = *(const float4*)&lnw[e];
        float4 lb = *(const float4*)&lnb[e];
        ushort4 un, ur;
        un.x = f2b((v[i].x - m) * rstd * lw.x + lb.x);
        un.y = f2b((v[i].y - m) * rstd * lw.y + lb.y);
        un.z = f2b((v[i].z - m) * rstd * lw.z + lb.z);
        un.w = f2b((v[i].w - m) * rstd * lw.w + lb.w);
        ur.x = f2b(v[i].x); ur.y = f2b(v[i].y); ur.z = f2b(v[i].z); ur.w = f2b(v[i].w);
        *(ushort4*)&xnb[(size_t)row * DIM + e] = un;
        *(ushort4*)&xb[(size_t)row * DIM + e] = ur;
    }
}

// ---------------------------------------------------------------------------
// Kernel 2: fp32 [K][N] weight -> bf16 transposed [N][K], via fp32 LDS tile.
// ---------------------------------------------------------------------------
__global__ __launch_bounds__(256) void wtrans_kernel(
    const float* __restrict__ W0, const float* __restrict__ W1,
    const float* __restrict__ W2, const float* __restrict__ W3,
    unsigned short* __restrict__ T0, unsigned short* __restrict__ T1,
    unsigned short* __restrict__ T2, unsigned short* __restrict__ T3) {
    __shared__ float tile[64][65];
    const int z = blockIdx.z;
    const float* W = (z == 0) ? W0 : (z == 1) ? W1 : (z == 2) ? W2 : W3;
    unsigned short* T = (z == 0) ? T0 : (z == 1) ? T1 : (z == 2) ? T2 : T3;
    const int k0 = blockIdx.x * 64, n0 = blockIdx.y * 64;
    const int r = threadIdx.x >> 3;
    const int c = (threadIdx.x & 7) * 8;
#pragma unroll
    for (int half = 0; half < 2; half++) {
        int rr = r + half * 32;
        float4 a = *(const float4*)&W[(size_t)(k0 + rr) * DIM + n0 + c];
        float4 b = *(const float4*)&W[(size_t)(k0 + rr) * DIM + n0 + c + 4];
        tile[rr][c + 0] = a.x; tile[rr][c + 1] = a.y; tile[rr][c + 2] = a.z; tile[rr][c + 3] = a.w;
        tile[rr][c + 4] = b.x; tile[rr][c + 5] = b.y; tile[rr][c + 6] = b.z; tile[rr][c + 7] = b.w;
    }
    __syncthreads();
#pragma unroll
    for (int half = 0; half < 2; half++) {
        int dd = r + half * 32;
        bf16x8 o;
#pragma unroll
        for (int j = 0; j < 8; j++) o[j] = (short)f2b(tile[c + j][dd]);
        *(bf16x8*)&T[(size_t)(n0 + dd) * DIM + k0 + c] = o;
    }
}

// ---------------------------------------------------------------------------
// Kernel 3: bf16 MFMA GEMM, 128x128 tile, BK=32, 4 waves (2x2).
// MODE 0: z=0/1 (Q/K): fused l2norm + gate in epilogue (each wave's 64-col
//         n-range is exactly one head; row lives in 16 lanes x 4 nt-tiles ->
//         shfl_xor reduction), writes normalized bf16 [B,H,T,hd] + gate[B,H,T].
//         z=2 (V): plain bf16 [B,H,T,hd].
// MODE 1: C = collb @ Wot^T + bias, fp32 out [B,T,D].
// ---------------------------------------------------------------------------
template <int MODE>
__global__ __launch_bounds__(256) void gemm_mfma_kernel(
    const unsigned short* __restrict__ A0, const unsigned short* __restrict__ A2,
    const unsigned short* __restrict__ Bt0, const unsigned short* __restrict__ Bt1,
    const unsigned short* __restrict__ Bt2, const float* __restrict__ bias,
    const float* __restrict__ gq, const float* __restrict__ gk,
    unsigned short* __restrict__ Oq, unsigned short* __restrict__ Ok,
    unsigned short* __restrict__ Ov, float* __restrict__ gq_t, float* __restrict__ gk_t,
    float* __restrict__ Oout) {
    __shared__ __align__(16) unsigned short As[128 * 32];
    __shared__ __align__(16) unsigned short Bs[128 * 32];
    const int tid = threadIdx.x;
    const int lane = tid & 63, w = tid >> 6;
    const int l16 = lane & 15, quad = lane >> 4;
    const int wm = w >> 1, wn = w & 1;
    const int m0 = blockIdx.x * 128, n0 = blockIdx.y * 128;
    const unsigned short* A;
    const unsigned short* Bt;
    int z = 0;
    if constexpr (MODE == 0) {
        z = blockIdx.z;
        A = (z == 2) ? A2 : A0;
        Bt = (z == 0) ? Bt0 : (z == 1) ? Bt1 : Bt2;
    } else {
        A = A0;
        Bt = Bt0;
    }
    f32x4 acc[4][4] = {};
    const int kswz = (l16 >> 1) & 3;

    for (int k0 = 0; k0 < DIM; k0 += 32) {
        __syncthreads();
#pragma unroll
        for (int i = 0; i < 2; i++) {
            int linear = i * 256 + tid;
            int m = linear >> 2, kgp = linear & 3;
            int kgl = kgp ^ ((m >> 1) & 3);
            async_cp16(A + (size_t)(m0 + m) * DIM + k0 + kgl * 8, As + linear * 8);
            async_cp16(Bt + (size_t)(n0 + m) * DIM + k0 + kgl * 8, Bs + linear * 8);
        }
        __syncthreads();
        bf16x8 af[4], bfr[4];
#pragma unroll
        for (int t = 0; t < 4; t++) {
            int ma = wm * 64 + t * 16 + l16;
            af[t] = *(const bf16x8*)(As + ma * 32 + ((quad ^ kswz) * 8));
            int nb = wn * 64 + t * 16 + l16;
            bfr[t] = *(const bf16x8*)(Bs + nb * 32 + ((quad ^ kswz) * 8));
        }
#pragma unroll
        for (int mt = 0; mt < 4; mt++)
#pragma unroll
            for (int nt = 0; nt < 4; nt++)
                acc[mt][nt] =
                    __builtin_amdgcn_mfma_f32_16x16x32_bf16(af[mt], bfr[nt], acc[mt][nt], 0, 0, 0);
    }

    if constexpr (MODE == 0) {
        const int h = (n0 + wn * 64) >> 6;  // this wave's head
        if (z <= 1) {
            const float* gvec = (z == 0) ? gq : gk;
            float* gate = (z == 0) ? gq_t : gk_t;
            unsigned short* O = (z == 0) ? Oq : Ok;
            float gv[4];
#pragma unroll
            for (int nt = 0; nt < 4; nt++) gv[nt] = gvec[nt * 16 + l16];
#pragma unroll
            for (int mt = 0; mt < 4; mt++) {
#pragma unroll
                for (int r = 0; r < 4; r++) {
                    float ss = 0.f;
#pragma unroll
                    for (int nt = 0; nt < 4; nt++) ss += acc[mt][nt][r] * acc[mt][nt][r];
#pragma unroll
                    for (int msk = 1; msk < 16; msk <<= 1) ss += __shfl_xor(ss, msk);
                    float rn = __builtin_amdgcn_rcpf(fmaxf(sqrtf(ss), 1e-12f));
                    float vn[4], gg = 0.f;
#pragma unroll
                    for (int nt = 0; nt < 4; nt++) {
                        vn[nt] = acc[mt][nt][r] * rn;
                        gg += vn[nt] * gv[nt];
                    }
#pragma unroll
                    for (int msk = 1; msk < 16; msk <<= 1) gg += __shfl_xor(gg, msk);
                    int tok = m0 + wm * 64 + mt * 16 + quad * 4 + r;
                    int b = tok >> 11, t = tok & 2047;
                    size_t rowbase = ((size_t)(b * HEADS + h) * T_SEQ + t) * HD;
#pragma unroll
                    for (int nt = 0; nt < 4; nt++) O[rowbase + nt * 16 + l16] = f2b(vn[nt]);
                    if (l16 == 0) gate[(b * HEADS + h) * T_SEQ + t] = gg;
                }
            }
        } else {
#pragma unroll
            for (int mt = 0; mt < 4; mt++) {
#pragma unroll
                for (int r = 0; r < 4; r++) {
                    int tok = m0 + wm * 64 + mt * 16 + quad * 4 + r;
                    int b = tok >> 11, t = tok & 2047;
                    size_t rowbase = ((size_t)(b * HEADS + h) * T_SEQ + t) * HD;
#pragma unroll
                    for (int nt = 0; nt < 4; nt++)
                        Ov[rowbase + nt * 16 + l16] = f2b(acc[mt][nt][r]);
                }
            }
        }
    } else {
        float bias_r[4];
#pragma unroll
        for (int nt = 0; nt < 4; nt++) bias_r[nt] = bias[n0 + wn * 64 + nt * 16 + l16];
#pragma unroll
        for (int mt = 0; mt < 4; mt++) {
#pragma unroll
            for (int r = 0; r < 4; r++) {
                int tok = m0 + wm * 64 + mt * 16 + quad * 4 + r;
#pragma unroll
                for (int nt = 0; nt < 4; nt++) {
                    int n = n0 + wn * 64 + nt * 16 + l16;
                    Oout[(size_t)tok * DIM + n] = acc[mt][nt][r] + bias_r[nt];
                }
            }
        }
    }
}

// ---------------------------------------------------------------------------
// Kernel 4: bf16 transpose V[bh][t][d] -> Vt[bh][d][t], fused gate_k scale
// (collapse = gq * sum_s res * (gk*V) is exact algebra). fp32 LDS tile.
// ---------------------------------------------------------------------------
__global__ __launch_bounds__(256) void vtrans_kernel(const unsigned short* __restrict__ Vn,
                                                     const float* __restrict__ gk_t,
                                                     unsigned short* __restrict__ Vt) {
    __shared__ float tile[64][65];
    const int bh = blockIdx.y;
    const int t0 = blockIdx.x * 64;
    const int r = threadIdx.x >> 3;
    const int c = (threadIdx.x & 7) * 8;
    const unsigned short* src = Vn + (size_t)bh * T_SEQ * HD;
#pragma unroll
    for (int half = 0; half < 2; half++) {
        int rr = r + half * 32;
        float gkv = gk_t[bh * T_SEQ + t0 + rr];
        bf16x8 v = *(const bf16x8*)(src + (size_t)(t0 + rr) * HD + c);
#pragma unroll
        for (int j = 0; j < 8; j++) tile[rr][c + j] = b2f((unsigned short)v[j]) * gkv;
    }
    __syncthreads();
    unsigned short* dst = Vt + (size_t)bh * HD * T_SEQ;
#pragma unroll
    for (int half = 0; half < 2; half++) {
        int dd = r + half * 32;
        bf16x8 o;
#pragma unroll
        for (int j = 0; j < 8; j++) o[j] = (short)f2b(tile[c + j][dd]);
        *(bf16x8*)(dst + (size_t)dd * T_SEQ + t0 + c) = o;
    }
}

// ---------------------------------------------------------------------------
// Kernel 5: MFMA gated attention. gate_k pre-folded into V; sigmoid via
// exp2+rcp (no fp32 divide). bf16 collapse epilogue (* gate_q).
// ---------------------------------------------------------------------------
__global__ __launch_bounds__(256) void attn_mfma_kernel(
    const unsigned short* __restrict__ Qn, const unsigned short* __restrict__ Kn,
    const unsigned short* __restrict__ Vt, const float* __restrict__ gateq,
    unsigned short* __restrict__ collb) {
    __shared__ __align__(16) unsigned short Ks[64 * 72];
    __shared__ __align__(16) unsigned short VtL[64 * 72];
    __shared__ __align__(16) unsigned short Sw[4 * 16 * 72];
    const int tid = threadIdx.x;
    const int lane = tid & 63, w = tid >> 6;
    const int quad = lane >> 4, l16 = lane & 15;
    const int t0 = blockIdx.x * 64;
    const int h = blockIdx.y, b = blockIdx.z;
    const int bh = b * HEADS + h;
    const size_t base = (size_t)bh * T_SEQ * HD;
    constexpr float K1 = -SHARP * LOG2E;          // -(a-T)*S*log2e = a*K1 + K0
    constexpr float K0 = THRESH * SHARP * LOG2E;

    const unsigned short* qrow = Qn + base + (size_t)(t0 + w * 16 + l16) * HD;
    bf16x8 fq0 = *(const bf16x8*)(qrow + quad * 8);
    bf16x8 fq1 = *(const bf16x8*)(qrow + 32 + quad * 8);

    f32x4 oacc[4] = {};
    unsigned short* myS = &Sw[w * 16 * 72];
    const int sr = tid >> 3;
    const int sc = (tid & 7) * 8;

    for (int s0 = 0; s0 < T_SEQ; s0 += 64) {
        __syncthreads();
#pragma unroll
        for (int half = 0; half < 2; half++) {
            int rr = sr + half * 32;
            bf16x8 kv = *(const bf16x8*)(Kn + base + (size_t)(s0 + rr) * HD + sc);
            *(bf16x8*)(Ks + rr * 72 + sc) = kv;
            bf16x8 vv = *(const bf16x8*)(Vt + base + (size_t)rr * T_SEQ + s0 + sc);
            *(bf16x8*)(VtL + rr * 72 + sc) = vv;
        }
        __syncthreads();

#pragma unroll
        for (int ct = 0; ct < 4; ct++) {
            f32x4 sacc = {0.f, 0.f, 0.f, 0.f};
            bf16x8 fk0 = *(const bf16x8*)(Ks + (ct * 16 + l16) * 72 + quad * 8);
            bf16x8 fk1 = *(const bf16x8*)(Ks + (ct * 16 + l16) * 72 + 32 + quad * 8);
            sacc = __builtin_amdgcn_mfma_f32_16x16x32_bf16(fq0, fk0, sacc, 0, 0, 0);
            sacc = __builtin_amdgcn_mfma_f32_16x16x32_bf16(fq1, fk1, sacc, 0, 0, 0);
#pragma unroll
            for (int r = 0; r < 4; r++) {
                float e = __builtin_amdgcn_exp2f(fmaf(sacc[r], K1, K0));
                float wv = __builtin_amdgcn_rcpf(1.f + e);
                myS[(quad * 4 + r) * 72 + ct * 16 + l16] = f2b(wv);
            }
        }
        __syncthreads();

        bf16x8 fs0 = *(const bf16x8*)(myS + l16 * 72 + quad * 8);
        bf16x8 fs1 = *(const bf16x8*)(myS + l16 * 72 + 32 + quad * 8);
#pragma unroll
        for (int dt = 0; dt < 4; dt++) {
            bf16x8 fv0 = *(const bf16x8*)(VtL + (dt * 16 + l16) * 72 + quad * 8);
            bf16x8 fv1 = *(const bf16x8*)(VtL + (dt * 16 + l16) * 72 + 32 + quad * 8);
            oacc[dt] = __builtin_amdgcn_mfma_f32_16x16x32_bf16(fs0, fv0, oacc[dt], 0, 0, 0);
            oacc[dt] = __builtin_amdgcn_mfma_f32_16x16x32_bf16(fs1, fv1, oacc[dt], 0, 0, 0);
        }
    }

#pragma unroll
    for (int r = 0; r < 4; r++) {
        int t = t0 + w * 16 + quad * 4 + r;
        float gq_v = gateq[bh * T_SEQ + t];
        unsigned short* dst = collb + ((size_t)b * T_SEQ + t) * DIM + h * HD;
#pragma unroll
        for (int dt = 0; dt < 4; dt++) dst[dt * 16 + l16] = f2b(oacc[dt][r] * gq_v);
    }
}

// ---------------------------------------------------------------------------
extern "C" void kernel_launch(void* const* d_in, const int* in_sizes, int n_in,
                              void* d_out, int out_size, void* d_ws, size_t ws_size,
                              hipStream_t stream) {
    const float* x = (const float*)d_in[0];
    const float* Wq = (const float*)d_in[1];
    const float* Wk = (const float*)d_in[2];
    const float* Wv = (const float*)d_in[3];
    const float* gq = (const float*)d_in[4];
    const float* gk = (const float*)d_in[5];
    const float* Wo = (const float*)d_in[6];
    const float* bo = (const float*)d_in[7];
    const float* lnw = (const float*)d_in[8];
    const float* lnb = (const float*)d_in[9];
    float* out = (float*)d_out;

    // Workspace ~51 MB. Aliases safe by stream ordering: Vt overwrites xnb
    // (dead after QKV GEMM); collb overwrites xb (dead after QKV GEMM).
    unsigned short* ws = (unsigned short*)d_ws;
    unsigned short* xnb = ws;                           // bf16 [4096][1024]
    unsigned short* xb = xnb + (size_t)NTOK * DIM;      // bf16 [4096][1024]
    unsigned short* Wqt = xb + (size_t)NTOK * DIM;      // bf16 [1024][1024] (W^T)
    unsigned short* Wkt = Wqt + (size_t)DIM * DIM;
    unsigned short* Wvt = Wkt + (size_t)DIM * DIM;
    unsigned short* Wot = Wvt + (size_t)DIM * DIM;
    unsigned short* Q16 = Wot + (size_t)DIM * DIM;      // bf16 [B,H,T,hd] (normalized)
    unsigned short* K16 = Q16 + (size_t)NTOK * DIM;     // bf16 (normalized)
    unsigned short* Vn = K16 + (size_t)NTOK * DIM;      // bf16 [B,H,T,hd]
    float* gq_t = (float*)(Vn + (size_t)NTOK * DIM);    // [B,H,T]
    float* gk_t = gq_t + NBATCH * HEADS * T_SEQ;
    unsigned short* Vt = xnb;    // alias: bf16 [B,H,hd,T], gk-scaled
    unsigned short* collb = xb;  // alias

    ln_xnorm_kernel<<<NTOK / 4, 256, 0, stream>>>(x, lnw, lnb, xnb, xb);
    wtrans_kernel<<<dim3(16, 16, 4), 256, 0, stream>>>(Wq, Wk, Wv, Wo, Wqt, Wkt, Wvt, Wot);
    gemm_mfma_kernel<0><<<dim3(NTOK / 128, DIM / 128, 3), 256, 0, stream>>>(
        xnb, xb, Wqt, Wkt, Wvt, nullptr, gq, gk, Q16, K16, Vn, gq_t, gk_t, nullptr);
    vtrans_kernel<<<dim3(T_SEQ / 64, NBATCH * HEADS), 256, 0, stream>>>(Vn, gk_t, Vt);
    attn_mfma_kernel<<<dim3(T_SEQ / 64, HEADS, NBATCH), 256, 0, stream>>>(
        Q16, K16, Vt, gq_t, collb);
    gemm_mfma_kernel<1><<<dim3(NTOK / 128, DIM / 128, 1), 256, 0, stream>>>(
        collb, nullptr, Wot, nullptr, nullptr, bo, nullptr, nullptr, nullptr, nullptr, nullptr,
        nullptr, nullptr, out);
}

// Round 6
// 236.591 us; speedup vs baseline: 5.7130x; 1.0602x over previous
//
#include <hip/hip_runtime.h>
#include <math.h>

#define DIM 1024
#define T_SEQ 2048
#define NBATCH 2
#define HEADS 16
#define HD 64
#define NTOK 4096  // NBATCH * T_SEQ
#define THRESH 0.29514f
#define SHARP 15.0f
#define LOG2E 1.4426950408889634f

typedef __attribute__((ext_vector_type(8))) short bf16x8;
typedef __attribute__((ext_vector_type(4))) float f32x4;

__device__ __forceinline__ unsigned short f2b(float f) {
    unsigned int u = __float_as_uint(f);
    unsigned int r = (u + 0x7FFFu + ((u >> 16) & 1u)) >> 16;
    return (unsigned short)r;
}
__device__ __forceinline__ float b2f(unsigned short u) {
    return __uint_as_float(((unsigned int)u) << 16);
}

__device__ __forceinline__ void async_cp16(const unsigned short* g, unsigned short* l) {
    __builtin_amdgcn_global_load_lds(
        (const __attribute__((address_space(1))) unsigned int*)g,
        (__attribute__((address_space(3))) unsigned int*)l, 16, 0, 0);
}

// ---------------------------------------------------------------------------
// Kernel 1: fused LayerNorm -> bf16 x_norm, plus bf16 cast of raw x.
// ---------------------------------------------------------------------------
__global__ __launch_bounds__(256) void ln_xnorm_kernel(
    const float* __restrict__ x, const float* __restrict__ lnw, const float* __restrict__ lnb,
    unsigned short* __restrict__ xnb, unsigned short* __restrict__ xb) {
    int row = blockIdx.x * 4 + (threadIdx.x >> 6);
    int lane = threadIdx.x & 63;
    const float4* xr = (const float4*)(x + (size_t)row * DIM);
    float4 v[4];
    float s = 0.f, ss = 0.f;
#pragma unroll
    for (int i = 0; i < 4; i++) {
        v[i] = xr[lane + i * 64];
        s += v[i].x + v[i].y + v[i].z + v[i].w;
        ss += v[i].x * v[i].x + v[i].y * v[i].y + v[i].z * v[i].z + v[i].w * v[i].w;
    }
#pragma unroll
    for (int off = 32; off; off >>= 1) {
        s += __shfl_xor(s, off);
        ss += __shfl_xor(ss, off);
    }
    float m = s * (1.f / DIM);
    float rstd = rsqrtf(ss * (1.f / DIM) - m * m + 1e-5f);
#pragma unroll
    for (int i = 0; i < 4; i++) {
        int e = (lane + i * 64) * 4;
        float4 lw = *(const float4*)&lnw[e];
        float4 lb = *(const float4*)&lnb[e];
        ushort4 un, ur;
        un.x = f2b((v[i].x - m) * rstd * lw.x + lb.x);
        un.y = f2b((v[i].y - m) * rstd * lw.y + lb.y);
        un.z = f2b((v[i].z - m) * rstd * lw.z + lb.z);
        un.w = f2b((v[i].w - m) * rstd * lw.w + lb.w);
        ur.x = f2b(v[i].x); ur.y = f2b(v[i].y); ur.z = f2b(v[i].z); ur.w = f2b(v[i].w);
        *(ushort4*)&xnb[(size_t)row * DIM + e] = un;
        *(ushort4*)&xb[(size_t)row * DIM + e] = ur;
    }
}

// ---------------------------------------------------------------------------
// Kernel 2: fp32 [K][N] weight -> bf16 transposed [N][K], via fp32 LDS tile.
// ---------------------------------------------------------------------------
__global__ __launch_bounds__(256) void wtrans_kernel(
    const float* __restrict__ W0, const float* __restrict__ W1,
    const float* __restrict__ W2, const float* __restrict__ W3,
    unsigned short* __restrict__ T0, unsigned short* __restrict__ T1,
    unsigned short* __restrict__ T2, unsigned short* __restrict__ T3) {
    __shared__ float tile[64][65];
    const int z = blockIdx.z;
    const float* W = (z == 0) ? W0 : (z == 1) ? W1 : (z == 2) ? W2 : W3;
    unsigned short* T = (z == 0) ? T0 : (z == 1) ? T1 : (z == 2) ? T2 : T3;
    const int k0 = blockIdx.x * 64, n0 = blockIdx.y * 64;
    const int r = threadIdx.x >> 3;
    const int c = (threadIdx.x & 7) * 8;
#pragma unroll
    for (int half = 0; half < 2; half++) {
        int rr = r + half * 32;
        float4 a = *(const float4*)&W[(size_t)(k0 + rr) * DIM + n0 + c];
        float4 b = *(const float4*)&W[(size_t)(k0 + rr) * DIM + n0 + c + 4];
        tile[rr][c + 0] = a.x; tile[rr][c + 1] = a.y; tile[rr][c + 2] = a.z; tile[rr][c + 3] = a.w;
        tile[rr][c + 4] = b.x; tile[rr][c + 5] = b.y; tile[rr][c + 6] = b.z; tile[rr][c + 7] = b.w;
    }
    __syncthreads();
#pragma unroll
    for (int half = 0; half < 2; half++) {
        int dd = r + half * 32;
        bf16x8 o;
#pragma unroll
        for (int j = 0; j < 8; j++) o[j] = (short)f2b(tile[c + j][dd]);
        *(bf16x8*)&T[(size_t)(n0 + dd) * DIM + k0 + c] = o;
    }
}

// ---------------------------------------------------------------------------
// Kernel 3: bf16 MFMA GEMM, 128x128 tile, BK=32, 4 waves (2x2).
// MODE 0: z=0/1 (Q/K): fused l2norm + gate in epilogue; z=2 (V): plain bf16.
// MODE 1: C = collb @ Wot^T + bias, fp32 out [B,T,D].
// ---------------------------------------------------------------------------
template <int MODE>
__global__ __launch_bounds__(256) void gemm_mfma_kernel(
    const unsigned short* __restrict__ A0, const unsigned short* __restrict__ A2,
    const unsigned short* __restrict__ Bt0, const unsigned short* __restrict__ Bt1,
    const unsigned short* __restrict__ Bt2, const float* __restrict__ bias,
    const float* __restrict__ gq, const float* __restrict__ gk,
    unsigned short* __restrict__ Oq, unsigned short* __restrict__ Ok,
    unsigned short* __restrict__ Ov, float* __restrict__ gq_t, float* __restrict__ gk_t,
    float* __restrict__ Oout) {
    __shared__ __align__(16) unsigned short As[128 * 32];
    __shared__ __align__(16) unsigned short Bs[128 * 32];
    const int tid = threadIdx.x;
    const int lane = tid & 63, w = tid >> 6;
    const int l16 = lane & 15, quad = lane >> 4;
    const int wm = w >> 1, wn = w & 1;
    const int m0 = blockIdx.x * 128, n0 = blockIdx.y * 128;
    const unsigned short* A;
    const unsigned short* Bt;
    int z = 0;
    if constexpr (MODE == 0) {
        z = blockIdx.z;
        A = (z == 2) ? A2 : A0;
        Bt = (z == 0) ? Bt0 : (z == 1) ? Bt1 : Bt2;
    } else {
        A = A0;
        Bt = Bt0;
    }
    f32x4 acc[4][4] = {};
    const int kswz = (l16 >> 1) & 3;

    for (int k0 = 0; k0 < DIM; k0 += 32) {
        __syncthreads();
#pragma unroll
        for (int i = 0; i < 2; i++) {
            int linear = i * 256 + tid;
            int m = linear >> 2, kgp = linear & 3;
            int kgl = kgp ^ ((m >> 1) & 3);
            async_cp16(A + (size_t)(m0 + m) * DIM + k0 + kgl * 8, As + linear * 8);
            async_cp16(Bt + (size_t)(n0 + m) * DIM + k0 + kgl * 8, Bs + linear * 8);
        }
        __syncthreads();
        bf16x8 af[4], bfr[4];
#pragma unroll
        for (int t = 0; t < 4; t++) {
            int ma = wm * 64 + t * 16 + l16;
            af[t] = *(const bf16x8*)(As + ma * 32 + ((quad ^ kswz) * 8));
            int nb = wn * 64 + t * 16 + l16;
            bfr[t] = *(const bf16x8*)(Bs + nb * 32 + ((quad ^ kswz) * 8));
        }
#pragma unroll
        for (int mt = 0; mt < 4; mt++)
#pragma unroll
            for (int nt = 0; nt < 4; nt++)
                acc[mt][nt] =
                    __builtin_amdgcn_mfma_f32_16x16x32_bf16(af[mt], bfr[nt], acc[mt][nt], 0, 0, 0);
    }

    if constexpr (MODE == 0) {
        const int h = (n0 + wn * 64) >> 6;  // this wave's head
        if (z <= 1) {
            const float* gvec = (z == 0) ? gq : gk;
            float* gate = (z == 0) ? gq_t : gk_t;
            unsigned short* O = (z == 0) ? Oq : Ok;
            float gv[4];
#pragma unroll
            for (int nt = 0; nt < 4; nt++) gv[nt] = gvec[nt * 16 + l16];
#pragma unroll
            for (int mt = 0; mt < 4; mt++) {
#pragma unroll
                for (int r = 0; r < 4; r++) {
                    float ss = 0.f;
#pragma unroll
                    for (int nt = 0; nt < 4; nt++) ss += acc[mt][nt][r] * acc[mt][nt][r];
#pragma unroll
                    for (int msk = 1; msk < 16; msk <<= 1) ss += __shfl_xor(ss, msk);
                    float rn = __builtin_amdgcn_rcpf(fmaxf(sqrtf(ss), 1e-12f));
                    float vn[4], gg = 0.f;
#pragma unroll
                    for (int nt = 0; nt < 4; nt++) {
                        vn[nt] = acc[mt][nt][r] * rn;
                        gg += vn[nt] * gv[nt];
                    }
#pragma unroll
                    for (int msk = 1; msk < 16; msk <<= 1) gg += __shfl_xor(gg, msk);
                    int tok = m0 + wm * 64 + mt * 16 + quad * 4 + r;
                    int b = tok >> 11, t = tok & 2047;
                    size_t rowbase = ((size_t)(b * HEADS + h) * T_SEQ + t) * HD;
#pragma unroll
                    for (int nt = 0; nt < 4; nt++) O[rowbase + nt * 16 + l16] = f2b(vn[nt]);
                    if (l16 == 0) gate[(b * HEADS + h) * T_SEQ + t] = gg;
                }
            }
        } else {
#pragma unroll
            for (int mt = 0; mt < 4; mt++) {
#pragma unroll
                for (int r = 0; r < 4; r++) {
                    int tok = m0 + wm * 64 + mt * 16 + quad * 4 + r;
                    int b = tok >> 11, t = tok & 2047;
                    size_t rowbase = ((size_t)(b * HEADS + h) * T_SEQ + t) * HD;
#pragma unroll
                    for (int nt = 0; nt < 4; nt++)
                        Ov[rowbase + nt * 16 + l16] = f2b(acc[mt][nt][r]);
                }
            }
        }
    } else {
        float bias_r[4];
#pragma unroll
        for (int nt = 0; nt < 4; nt++) bias_r[nt] = bias[n0 + wn * 64 + nt * 16 + l16];
#pragma unroll
        for (int mt = 0; mt < 4; mt++) {
#pragma unroll
            for (int r = 0; r < 4; r++) {
                int tok = m0 + wm * 64 + mt * 16 + quad * 4 + r;
#pragma unroll
                for (int nt = 0; nt < 4; nt++) {
                    int n = n0 + wn * 64 + nt * 16 + l16;
                    Oout[(size_t)tok * DIM + n] = acc[mt][nt][r] + bias_r[nt];
                }
            }
        }
    }
}

// ---------------------------------------------------------------------------
// Kernel 4: bf16 transpose V[bh][t][d] -> Vt[bh][d][t], fused gate_k scale.
// ---------------------------------------------------------------------------
__global__ __launch_bounds__(256) void vtrans_kernel(const unsigned short* __restrict__ Vn,
                                                     const float* __restrict__ gk_t,
                                                     unsigned short* __restrict__ Vt) {
    __shared__ float tile[64][65];
    const int bh = blockIdx.y;
    const int t0 = blockIdx.x * 64;
    const int r = threadIdx.x >> 3;
    const int c = (threadIdx.x & 7) * 8;
    const unsigned short* src = Vn + (size_t)bh * T_SEQ * HD;
#pragma unroll
    for (int half = 0; half < 2; half++) {
        int rr = r + half * 32;
        float gkv = gk_t[bh * T_SEQ + t0 + rr];
        bf16x8 v = *(const bf16x8*)(src + (size_t)(t0 + rr) * HD + c);
#pragma unroll
        for (int j = 0; j < 8; j++) tile[rr][c + j] = b2f((unsigned short)v[j]) * gkv;
    }
    __syncthreads();
    unsigned short* dst = Vt + (size_t)bh * HD * T_SEQ;
#pragma unroll
    for (int half = 0; half < 2; half++) {
        int dd = r + half * 32;
        bf16x8 o;
#pragma unroll
        for (int j = 0; j < 8; j++) o[j] = (short)f2b(tile[c + j][dd]);
        *(bf16x8*)(dst + (size_t)dd * T_SEQ + t0 + c) = o;
    }
}

// ---------------------------------------------------------------------------
// Kernel 5: MFMA gated attention, restructured.
// Block = 4 waves x 32 q-rows = 128 rows. s-chunks of 64, double-buffered
// K/Vt in LDS (1 barrier/chunk). QK^T computed transposed (S^T = K Q^T via
// operand swap) so each lane holds 4 consecutive s -> packed ds_write_b64
// into the wave-private S tile (no barrier needed before SV). SV computed
// as O^T = V^T S^T. gate_k pre-folded into V; gate_q at epilogue.
// ---------------------------------------------------------------------------
__global__ __launch_bounds__(256) void attn_mfma_kernel(
    const unsigned short* __restrict__ Qn, const unsigned short* __restrict__ Kn,
    const unsigned short* __restrict__ Vt, const float* __restrict__ gateq,
    unsigned short* __restrict__ collb) {
    __shared__ __align__(16) unsigned short Ks[2][64 * 72];   // [s][d] stride 72
    __shared__ __align__(16) unsigned short VtL[2][64 * 72];  // [d][s] stride 72
    __shared__ __align__(16) unsigned short Sw[4][32 * 72];   // per-wave [m][s]
    const int tid = threadIdx.x;
    const int lane = tid & 63, w = tid >> 6;
    const int quad = lane >> 4, l16 = lane & 15;
    const int t0 = blockIdx.x * 128;
    const int h = blockIdx.y, b = blockIdx.z;
    const int bh = b * HEADS + h;
    const size_t base = (size_t)bh * T_SEQ * HD;  // == bh*HD*T_SEQ for Vt
    constexpr float K1 = -SHARP * LOG2E;
    constexpr float K0 = THRESH * SHARP * LOG2E;

    // Q fragments: 32 rows per wave, 2 m-tiles (registers, whole kernel)
    bf16x8 fq[2][2];
#pragma unroll
    for (int mt = 0; mt < 2; mt++) {
        const unsigned short* qrow = Qn + base + (size_t)(t0 + w * 32 + mt * 16 + l16) * HD;
        fq[mt][0] = *(const bf16x8*)(qrow + quad * 8);
        fq[mt][1] = *(const bf16x8*)(qrow + 32 + quad * 8);
    }

    f32x4 oacc[4][2] = {};  // [dt][mtile], O^T C-layout
    unsigned short* myS = Sw[w];
    const int sr = tid >> 3;       // staging row 0..31
    const int sc = (tid & 7) * 8;  // staging col (elements)

    // prologue: stage chunk 0 into buffer 0
    bf16x8 kr0, kr1, vr0, vr1;
    kr0 = *(const bf16x8*)(Kn + base + (size_t)sr * HD + sc);
    kr1 = *(const bf16x8*)(Kn + base + (size_t)(sr + 32) * HD + sc);
    vr0 = *(const bf16x8*)(Vt + base + (size_t)sr * T_SEQ + sc);
    vr1 = *(const bf16x8*)(Vt + base + (size_t)(sr + 32) * T_SEQ + sc);
    *(bf16x8*)(Ks[0] + sr * 72 + sc) = kr0;
    *(bf16x8*)(Ks[0] + (sr + 32) * 72 + sc) = kr1;
    *(bf16x8*)(VtL[0] + sr * 72 + sc) = vr0;
    *(bf16x8*)(VtL[0] + (sr + 32) * 72 + sc) = vr1;
    __syncthreads();

    for (int i = 0; i < T_SEQ / 64; i++) {
        const unsigned short* ksb = Ks[i & 1];
        const unsigned short* vtb = VtL[i & 1];
        const bool more = (i + 1) < (T_SEQ / 64);
        if (more) {  // prefetch next chunk into registers (overlaps compute)
            int s0n = (i + 1) * 64;
            kr0 = *(const bf16x8*)(Kn + base + (size_t)(s0n + sr) * HD + sc);
            kr1 = *(const bf16x8*)(Kn + base + (size_t)(s0n + sr + 32) * HD + sc);
            vr0 = *(const bf16x8*)(Vt + base + (size_t)sr * T_SEQ + s0n + sc);
            vr1 = *(const bf16x8*)(Vt + base + (size_t)(sr + 32) * T_SEQ + s0n + sc);
        }

        // ---- QK phase: S^T = K Q^T (operand swap), sigmoid, b64 S-writes ----
#pragma unroll
        for (int ct = 0; ct < 4; ct++) {
            bf16x8 fk0 = *(const bf16x8*)(ksb + (ct * 16 + l16) * 72 + quad * 8);
            bf16x8 fk1 = *(const bf16x8*)(ksb + (ct * 16 + l16) * 72 + 32 + quad * 8);
#pragma unroll
            for (int mt = 0; mt < 2; mt++) {
                f32x4 sacc = {0.f, 0.f, 0.f, 0.f};
                sacc = __builtin_amdgcn_mfma_f32_16x16x32_bf16(fk0, fq[mt][0], sacc, 0, 0, 0);
                sacc = __builtin_amdgcn_mfma_f32_16x16x32_bf16(fk1, fq[mt][1], sacc, 0, 0, 0);
                ushort4 p;
                p.x = f2b(__builtin_amdgcn_rcpf(1.f + __builtin_amdgcn_exp2f(fmaf(sacc[0], K1, K0))));
                p.y = f2b(__builtin_amdgcn_rcpf(1.f + __builtin_amdgcn_exp2f(fmaf(sacc[1], K1, K0))));
                p.z = f2b(__builtin_amdgcn_rcpf(1.f + __builtin_amdgcn_exp2f(fmaf(sacc[2], K1, K0))));
                p.w = f2b(__builtin_amdgcn_rcpf(1.f + __builtin_amdgcn_exp2f(fmaf(sacc[3], K1, K0))));
                // lane holds S[m=mt*16+l16][s=ct*16+quad*4 .. +3] -> one b64
                *(ushort4*)(myS + (mt * 16 + l16) * 72 + ct * 16 + quad * 4) = p;
            }
        }
        // Sw is wave-private: in-order LDS within the wave, no barrier needed.

        // ---- SV phase: O^T += V^T S^T ----
#pragma unroll
        for (int kh = 0; kh < 2; kh++) {
            bf16x8 fs0 = *(const bf16x8*)(myS + (0 * 16 + l16) * 72 + kh * 32 + quad * 8);
            bf16x8 fs1 = *(const bf16x8*)(myS + (1 * 16 + l16) * 72 + kh * 32 + quad * 8);
#pragma unroll
            for (int dt = 0; dt < 4; dt++) {
                bf16x8 fv = *(const bf16x8*)(vtb + (dt * 16 + l16) * 72 + kh * 32 + quad * 8);
                oacc[dt][0] = __builtin_amdgcn_mfma_f32_16x16x32_bf16(fv, fs0, oacc[dt][0], 0, 0, 0);
                oacc[dt][1] = __builtin_amdgcn_mfma_f32_16x16x32_bf16(fv, fs1, oacc[dt][1], 0, 0, 0);
            }
        }

        if (more) {  // write prefetched chunk into the other buffer
            unsigned short* ksn = Ks[(i + 1) & 1];
            unsigned short* vtn = VtL[(i + 1) & 1];
            *(bf16x8*)(ksn + sr * 72 + sc) = kr0;
            *(bf16x8*)(ksn + (sr + 32) * 72 + sc) = kr1;
            *(bf16x8*)(vtn + sr * 72 + sc) = vr0;
            *(bf16x8*)(vtn + (sr + 32) * 72 + sc) = vr1;
        }
        __syncthreads();
    }

    // ---- epilogue: O^T lanes hold 4 consecutive d; * gate_q, b64 writes ----
#pragma unroll
    for (int mt = 0; mt < 2; mt++) {
        int t = t0 + w * 32 + mt * 16 + l16;
        float gq_v = gateq[bh * T_SEQ + t];
        unsigned short* dst = collb + ((size_t)b * T_SEQ + t) * DIM + h * HD;
#pragma unroll
        for (int dt = 0; dt < 4; dt++) {
            ushort4 o;
            o.x = f2b(oacc[dt][mt][0] * gq_v);
            o.y = f2b(oacc[dt][mt][1] * gq_v);
            o.z = f2b(oacc[dt][mt][2] * gq_v);
            o.w = f2b(oacc[dt][mt][3] * gq_v);
            *(ushort4*)(dst + dt * 16 + quad * 4) = o;
        }
    }
}

// ---------------------------------------------------------------------------
extern "C" void kernel_launch(void* const* d_in, const int* in_sizes, int n_in,
                              void* d_out, int out_size, void* d_ws, size_t ws_size,
                              hipStream_t stream) {
    const float* x = (const float*)d_in[0];
    const float* Wq = (const float*)d_in[1];
    const float* Wk = (const float*)d_in[2];
    const float* Wv = (const float*)d_in[3];
    const float* gq = (const float*)d_in[4];
    const float* gk = (const float*)d_in[5];
    const float* Wo = (const float*)d_in[6];
    const float* bo = (const float*)d_in[7];
    const float* lnw = (const float*)d_in[8];
    const float* lnb = (const float*)d_in[9];
    float* out = (float*)d_out;

    // Workspace ~51 MB. Aliases safe by stream ordering: Vt overwrites xnb
    // (dead after QKV GEMM); collb overwrites xb (dead after QKV GEMM).
    unsigned short* ws = (unsigned short*)d_ws;
    unsigned short* xnb = ws;                           // bf16 [4096][1024]
    unsigned short* xb = xnb + (size_t)NTOK * DIM;      // bf16 [4096][1024]
    unsigned short* Wqt = xb + (size_t)NTOK * DIM;      // bf16 [1024][1024] (W^T)
    unsigned short* Wkt = Wqt + (size_t)DIM * DIM;
    unsigned short* Wvt = Wkt + (size_t)DIM * DIM;
    unsigned short* Wot = Wvt + (size_t)DIM * DIM;
    unsigned short* Q16 = Wot + (size_t)DIM * DIM;      // bf16 [B,H,T,hd] (normalized)
    unsigned short* K16 = Q16 + (size_t)NTOK * DIM;     // bf16 (normalized)
    unsigned short* Vn = K16 + (size_t)NTOK * DIM;      // bf16 [B,H,T,hd]
    float* gq_t = (float*)(Vn + (size_t)NTOK * DIM);    // [B,H,T]
    float* gk_t = gq_t + NBATCH * HEADS * T_SEQ;
    unsigned short* Vt = xnb;    // alias: bf16 [B,H,hd,T], gk-scaled
    unsigned short* collb = xb;  // alias

    ln_xnorm_kernel<<<NTOK / 4, 256, 0, stream>>>(x, lnw, lnb, xnb, xb);
    wtrans_kernel<<<dim3(16, 16, 4), 256, 0, stream>>>(Wq, Wk, Wv, Wo, Wqt, Wkt, Wvt, Wot);
    gemm_mfma_kernel<0><<<dim3(NTOK / 128, DIM / 128, 3), 256, 0, stream>>>(
        xnb, xb, Wqt, Wkt, Wvt, nullptr, gq, gk, Q16, K16, Vn, gq_t, gk_t, nullptr);
    vtrans_kernel<<<dim3(T_SEQ / 64, NBATCH * HEADS), 256, 0, stream>>>(Vn, gk_t, Vt);
    attn_mfma_kernel<<<dim3(T_SEQ / 128, HEADS, NBATCH), 256, 0, stream>>>(
        Q16, K16, Vt, gq_t, collb);
    gemm_mfma_kernel<1><<<dim3(NTOK / 128, DIM / 128, 1), 256, 0, stream>>>(
        collb, nullptr, Wot, nullptr, nullptr, bo, nullptr, nullptr, nullptr, nullptr, nullptr,
        nullptr, nullptr, out);
}